// Round 2
// baseline (264.724 us; speedup 1.0000x reference)
//
#include <hip/hip_runtime.h>
#include <hip/hip_bf16.h>

#define B 4096
#define DFEAT 128
#define NCLS 512
#define NEG_INF_F (-1e30f)

typedef __attribute__((ext_vector_type(8))) short bf16x8;
typedef __attribute__((ext_vector_type(4))) float f32x4;

__device__ __forceinline__ unsigned short f2bf(float f) {
    unsigned int u = __float_as_uint(f);
    unsigned int r = (u + 0x7fffu + ((u >> 16) & 1u)) >> 16;
    return (unsigned short)r;
}

// online softmax-weighted accumulation: add one entry with given logit, value d
__device__ __forceinline__ void oupd(float logit, float d, float& m, float& sw, float& swd) {
    if (logit > m) {
        float e = __expf(m - logit);   // m==-1e30 -> e==0 -> resets cleanly
        sw  = fmaf(sw, e, 1.0f);
        swd = fmaf(swd, e, d);
        m = logit;
    } else {
        float e = __expf(logit - m);
        sw += e;
        swd = fmaf(e, d, swd);
    }
}

// merge two online-softmax states (m2,sw2,swd2) into (m,sw,swd)
__device__ __forceinline__ void omerge(float& m, float& sw, float& swd,
                                       float m2, float sw2, float swd2) {
    float M = fmaxf(m, m2);
    float e1 = __expf(m - M);
    float e2 = __expf(m2 - M);
    sw  = sw * e1 + sw2 * e2;
    swd = swd * e1 + swd2 * e2;
    m = M;
}

__device__ __forceinline__ void wave_reduce12(float st[12]) {
    #pragma unroll
    for (int off = 32; off; off >>= 1) {
        float o[12];
        #pragma unroll
        for (int k = 0; k < 12; ++k) o[k] = __shfl_down(st[k], off);
        omerge(st[0], st[1], st[2], o[0], o[1], o[2]);
        omerge(st[3], st[4], st[5], o[3], o[4], o[5]);
        omerge(st[6], st[7], st[8], o[6], o[7], o[8]);
        st[9] += o[9]; st[10] += o[10]; st[11] += o[11];
    }
}

// ---------------- kernel 1: x -> bf16 copy + row sum-of-squares ----------------
__global__ void prep_kernel(const float* __restrict__ x,
                            unsigned int* __restrict__ xbf_packed,
                            float* __restrict__ sq) {
    int row = blockIdx.x;
    int lane = threadIdx.x;  // 64
    float2 v = ((const float2*)(x + row * DFEAT))[lane];
    float ss = fmaf(v.x, v.x, v.y * v.y);
    unsigned int pk = ((unsigned int)f2bf(v.y) << 16) | (unsigned int)f2bf(v.x);
    xbf_packed[row * (DFEAT / 2) + lane] = pk;
    #pragma unroll
    for (int off = 32; off; off >>= 1) ss += __shfl_down(ss, off);
    if (lane == 0) sq[row] = ss;
}

// ---------------- kernel 2: dist tile + masked partial reductions ----------------
__launch_bounds__(256)
__global__ void dist_loss_kernel(const unsigned short* __restrict__ xbf,
                                 const float* __restrict__ sq,
                                 const int* __restrict__ y,
                                 const float* __restrict__ meant,
                                 const float* __restrict__ stdt,
                                 const float* __restrict__ noise,
                                 float* __restrict__ out,
                                 float* __restrict__ partials) {
    const int bx = blockIdx.x;       // col tile
    const int by = blockIdx.y;       // row tile
    const int bid = by * 32 + bx;
    const int tid = threadIdx.x;
    const int wave = tid >> 6;
    const int lane = tid & 63;
    const int q = lane >> 4;         // 0..3
    const int l16 = lane & 15;
    const int row0 = by * 128 + (wave >> 1) * 64;
    const int col0 = bx * 128 + (wave & 1) * 64;

    f32x4 acc[4][4];
    #pragma unroll
    for (int r = 0; r < 4; ++r)
        #pragma unroll
        for (int c = 0; c < 4; ++c)
            acc[r][c] = (f32x4){0.f, 0.f, 0.f, 0.f};

    // K loop: 4 x (K=32). A and B fragments are the same gather pattern from x.
    #pragma unroll
    for (int kk = 0; kk < 4; ++kk) {
        const int ko = kk * 32 + q * 8;
        bf16x8 afr[4], bfr[4];
        #pragma unroll
        for (int r = 0; r < 4; ++r)
            afr[r] = *(const bf16x8*)(xbf + (row0 + r * 16 + l16) * DFEAT + ko);
        #pragma unroll
        for (int c = 0; c < 4; ++c)
            bfr[c] = *(const bf16x8*)(xbf + (col0 + c * 16 + l16) * DFEAT + ko);
        #pragma unroll
        for (int r = 0; r < 4; ++r)
            #pragma unroll
            for (int c = 0; c < 4; ++c)
                acc[r][c] = __builtin_amdgcn_mfma_f32_16x16x32_bf16(afr[r], bfr[c], acc[r][c], 0, 0, 0);
    }

    int cols[4]; float sqc[4];
    #pragma unroll
    for (int c = 0; c < 4; ++c) {
        cols[c] = col0 + c * 16 + l16;
        sqc[c] = sq[cols[c]];
    }

    if (bx < by) {
        // fully lower-triangle block: write dist only, neutral partials
        #pragma unroll
        for (int r = 0; r < 4; ++r) {
            #pragma unroll
            for (int t = 0; t < 4; ++t) {
                int row = row0 + r * 16 + q * 4 + t;
                float sqr = sq[row];
                int base = row * B;
                #pragma unroll
                for (int c = 0; c < 4; ++c)
                    out[base + cols[c]] = fmaf(-2.0f, acc[r][c][t], sqr + sqc[c]);
            }
        }
        if (tid == 0) {
            float* pp = partials + bid * 12;
            pp[0] = NEG_INF_F; pp[1] = 0.f; pp[2] = 0.f;
            pp[3] = NEG_INF_F; pp[4] = 0.f; pp[5] = 0.f;
            pp[6] = NEG_INF_F; pp[7] = 0.f; pp[8] = 0.f;
            pp[9] = 0.f; pp[10] = 0.f; pp[11] = 0.f;
        }
        return;
    }

    int yj[4];
    #pragma unroll
    for (int c = 0; c < 4; ++c) yj[c] = y[cols[c]];

    // st: [0..2]=n1(m,sw,swd) [3..5]=n2 [6..8]=n3 [9..11]=(ps,ps2,cnt)
    float st[12];
    st[0] = st[3] = st[6] = NEG_INF_F;
    st[1] = st[2] = st[4] = st[5] = st[7] = st[8] = st[9] = st[10] = st[11] = 0.f;

    #pragma unroll
    for (int r = 0; r < 4; ++r) {
        #pragma unroll
        for (int t = 0; t < 4; ++t) {
            int row = row0 + r * 16 + q * 4 + t;
            float sqr = sq[row];
            int yi = y[row];
            int base = row * B;
            #pragma unroll
            for (int c = 0; c < 4; ++c) {
                int col = cols[c];
                float d = fmaf(-2.0f, acc[r][c][t], sqr + sqc[c]);
                out[base + col] = d;
                if (col > row) {
                    float nz = noise[base + col];
                    int idx = yi * NCLS + yj[c];
                    float mu = meant[idx];
                    float sg = stdt[idx];
                    float obs = fmaf(sg, nz, mu);
                    if ((row >> 3) == (col >> 3)) {
                        // positive pair
                        float thr_p = fmaf(2.0f, sg, obs);
                        if (d > thr_p) {
                            st[9] += d; st[10] = fmaf(d, d, st[10]); st[11] += 1.0f;
                        }
                    } else {
                        float t1 = fmaf(-2.5f, sg, obs);
                        if (d < t1) {
                            oupd(10.0f * (t1 - d), d, st[0], st[1], st[2]);
                        } else {
                            float tm = fmaf(-1.5f, sg, obs);
                            if (d < tm) {
                                if (d > t1) oupd(5.0f * (tm - d), d, st[3], st[4], st[5]);
                            } else {
                                float th = fmaf(1.5f, sg, obs);
                                if (d < th && d > tm) oupd(5.0f * (th - d), d, st[6], st[7], st[8]);
                            }
                        }
                    }
                }
            }
        }
    }

    wave_reduce12(st);

    __shared__ float red[4][12];
    if (lane == 0) {
        #pragma unroll
        for (int k = 0; k < 12; ++k) red[wave][k] = st[k];
    }
    __syncthreads();
    if (tid == 0) {
        float r0[12];
        #pragma unroll
        for (int k = 0; k < 12; ++k) r0[k] = red[0][k];
        #pragma unroll
        for (int w = 1; w < 4; ++w) {
            omerge(r0[0], r0[1], r0[2], red[w][0], red[w][1], red[w][2]);
            omerge(r0[3], r0[4], r0[5], red[w][3], red[w][4], red[w][5]);
            omerge(r0[6], r0[7], r0[8], red[w][6], red[w][7], red[w][8]);
            r0[9] += red[w][9]; r0[10] += red[w][10]; r0[11] += red[w][11];
        }
        float* pp = partials + bid * 12;
        #pragma unroll
        for (int k = 0; k < 12; ++k) pp[k] = r0[k];
    }
}

// ---------------- kernel 3: final reduction + loss ----------------
__global__ void finalize_kernel(const float* __restrict__ partials,
                                float* __restrict__ out) {
    int tid = threadIdx.x;  // 256
    int lane = tid & 63, wave = tid >> 6;
    float st[12];
    st[0] = st[3] = st[6] = NEG_INF_F;
    st[1] = st[2] = st[4] = st[5] = st[7] = st[8] = st[9] = st[10] = st[11] = 0.f;
    for (int p = tid; p < 1024; p += 256) {
        const float* pp = partials + p * 12;
        omerge(st[0], st[1], st[2], pp[0], pp[1], pp[2]);
        omerge(st[3], st[4], st[5], pp[3], pp[4], pp[5]);
        omerge(st[6], st[7], st[8], pp[6], pp[7], pp[8]);
        st[9] += pp[9]; st[10] += pp[10]; st[11] += pp[11];
    }
    wave_reduce12(st);
    __shared__ float red[4][12];
    if (lane == 0) {
        #pragma unroll
        for (int k = 0; k < 12; ++k) red[wave][k] = st[k];
    }
    __syncthreads();
    if (tid == 0) {
        float r0[12];
        #pragma unroll
        for (int k = 0; k < 12; ++k) r0[k] = red[0][k];
        #pragma unroll
        for (int w = 1; w < 4; ++w) {
            omerge(r0[0], r0[1], r0[2], red[w][0], red[w][1], red[w][2]);
            omerge(r0[3], r0[4], r0[5], red[w][3], red[w][4], red[w][5]);
            omerge(r0[6], r0[7], r0[8], red[w][6], red[w][7], red[w][8]);
            r0[9] += red[w][9]; r0[10] += red[w][10]; r0[11] += red[w][11];
        }
        float ln1 = (r0[1] > 0.f) ? -(r0[2] / r0[1]) : -0.0001f;
        float ln2 = (r0[4] > 0.f) ? -(r0[5] / r0[4]) : -0.0001f;
        float ln3 = (r0[7] > 0.f) ? -(r0[8] / r0[7]) : -0.0001f;
        float lp  = (r0[11] > 0.f) ? (r0[10] / ((r0[9] != 0.f) ? r0[9] : 1.f)) : 0.0001f;
        out[(size_t)B * B] = 1.0f + 0.25f * (ln1 + ln2 + ln3 + lp);
    }
}

extern "C" void kernel_launch(void* const* d_in, const int* in_sizes, int n_in,
                              void* d_out, int out_size, void* d_ws, size_t ws_size,
                              hipStream_t stream) {
    const float* x     = (const float*)d_in[0];
    const int*   y     = (const int*)d_in[1];
    const float* meant = (const float*)d_in[2];
    const float* stdt  = (const float*)d_in[3];
    const float* noise = (const float*)d_in[4];
    float* out = (float*)d_out;
    char* ws = (char*)d_ws;
    unsigned short* xbf = (unsigned short*)ws;            // 4096*128*2 = 1 MiB
    float* sq           = (float*)(ws + 1048576);         // 16 KiB
    float* partials     = (float*)(ws + 1064960);         // 1024*12*4 = 48 KiB

    hipLaunchKernelGGL(prep_kernel, dim3(B), dim3(64), 0, stream,
                       x, (unsigned int*)xbf, sq);
    hipLaunchKernelGGL(dist_loss_kernel, dim3(32, 32), dim3(256), 0, stream,
                       xbf, sq, y, meant, stdt, noise, out, partials);
    hipLaunchKernelGGL(finalize_kernel, dim3(1), dim3(256), 0, stream,
                       partials, out);
}